// Round 17
// baseline (607.955 us; speedup 1.0000x reference)
//
#include <hip/hip_runtime.h>
#include <math.h>

namespace {

constexpr int NA  = 50000;
constexpr int NE  = 1600000;
constexpr int NM  = 500;
constexpr int H   = 128;
constexpr int G   = 50;
constexpr int L   = 6;
constexpr int TBL = 8192;
constexpr int TSTR = (TBL + 1) * H;     // per-layer wtab stride; ROW 0 = zero row, data rows 1..TBL
constexpr int PAD = 80;
constexpr float DMAX = 5.6f;            // beyond 5.6 the Gaussian envelope is <3e-8; do NOT lower
                                        // (C(d) rises again past d=5 — round 9 lesson)
constexpr int SB  = 64;                 // sort blocks
constexpr int SCH = (NA + SB - 1) / SB; // 782 atoms per sort block

typedef _Float16 half8 __attribute__((ext_vector_type(8)));
typedef _Float16 half4 __attribute__((ext_vector_type(4)));
typedef float f32x4 __attribute__((ext_vector_type(4)));
struct hpair { _Float16 x, y; };

__device__ __forceinline__ float sspf(float v) {
    // softplus(v) - ln2 via native exp/log
    return fmaxf(v, 0.0f) + __logf(1.0f + __expf(-fabsf(v))) - 0.6931471805599453f;
}
__device__ __forceinline__ unsigned short f2h(float f) {
    _Float16 h = (_Float16)f;
    return __builtin_bit_cast(unsigned short, h);
}
__device__ __forceinline__ half8 cvt8(float4 a, float4 b) {
    half8 r;
    r[0] = (_Float16)a.x; r[1] = (_Float16)a.y; r[2] = (_Float16)a.z; r[3] = (_Float16)a.w;
    r[4] = (_Float16)b.x; r[5] = (_Float16)b.y; r[6] = (_Float16)b.z; r[7] = (_Float16)b.w;
    return r;
}
__device__ __forceinline__ float hlo(unsigned v) {
    return (float)__builtin_bit_cast(hpair, v).x;
}
__device__ __forceinline__ float hhi(unsigned v) {
    return (float)__builtin_bit_cast(hpair, v).y;
}
// B^T LDS granule offset with XOR swizzle for 128-u16 row pitch (16B granules)
__device__ __forceinline__ int bofs(int nrow, int g) {   // g = 16B granule 0..15
    int gs = (g & 8) | ((g ^ nrow) & 7);
    return nrow * 128 + gs * 8;
}
// Ts f16 [128][128], swizzled on 8B granules (4 f16); ~2-way bank access (free per m136)
__device__ __forceinline__ int off8(int row, int g) {   // g = col>>2, 0..31
    int gs = (g & 24) | ((g ^ row) & 7);
    return (row << 7) + (gs << 2);
}
__device__ __forceinline__ half8 ts_read(const _Float16* Ts, int row, int col0) {
    int g0 = col0 >> 2;
    half4 a = *(const half4*)&Ts[off8(row, g0)];
    half4 b = *(const half4*)&Ts[off8(row, g0 + 1)];
    half8 r;
    r[0] = a[0]; r[1] = a[1]; r[2] = a[2]; r[3] = a[3];
    r[4] = b[0]; r[5] = b[1]; r[6] = b[2]; r[7] = b[3];
    return r;
}

// ---------------- preprocessing: one-pass padded-CSR build, 4 edges/thread ----------------
// meta pre-zeroed; pad slots stay 0 -> (s=0, wtab row 0 = zero row) -> contribute 0.

__global__ void edge_build(const float* __restrict__ pos, const int* __restrict__ ei,
                           int* __restrict__ counts, unsigned* __restrict__ meta) {
    int e0 = (blockIdx.x * 256 + threadIdx.x) << 2;
    if (e0 >= NE) return;
    int4 sv = *(const int4*)&ei[e0];
    int4 tv = *(const int4*)&ei[NE + e0];
    int ss[4] = {sv.x, sv.y, sv.z, sv.w};
    int tt[4] = {tv.x, tv.y, tv.z, tv.w};
    float ux[4];
    #pragma unroll
    for (int j = 0; j < 4; ++j) {
        float dx = pos[3*ss[j]]   - pos[3*tt[j]];
        float dy = pos[3*ss[j]+1] - pos[3*tt[j]+1];
        float dz = pos[3*ss[j]+2] - pos[3*tt[j]+2];
        ux[j] = sqrtf(dx*dx + dy*dy + dz*dz + 1e-12f) * ((float)(TBL - 1) / DMAX);
    }
    #pragma unroll
    for (int j = 0; j < 4; ++j) {
        if (ux[j] < (float)(TBL - 1)) {
            int idx = (int)(ux[j] + 0.5f) + 1;       // rows 1..TBL
            int r = atomicAdd(&counts[tt[j]], 1);
            if (r < PAD) meta[(size_t)tt[j] * PAD + r] = (unsigned)ss[j] | ((unsigned)idx << 16);
        }
    }
}

// ---------------- parallel counting sort (64 blocks, LDS atomics) ----------------

__global__ __launch_bounds__(256) void sort_hist(const int* __restrict__ deg,
                                                 int* __restrict__ part) {
    __shared__ int bins[PAD + 1];
    int b = blockIdx.x, tid = threadIdx.x;
    if (tid <= PAD) bins[tid] = 0;
    __syncthreads();
    int i0 = b * SCH, i1 = min(i0 + SCH, NA);
    for (int i = i0 + tid; i < i1; i += 256)
        atomicAdd(&bins[min(deg[i], PAD)], 1);
    __syncthreads();
    if (tid <= PAD) part[b * (PAD + 1) + tid] = bins[tid];
}

__global__ __launch_bounds__(128) void sort_scan(int* __restrict__ part) {
    __shared__ int totals[PAD + 1];
    int b = threadIdx.x;
    if (b <= PAD) {
        int s = 0;
        for (int k = 0; k < SB; ++k) s += part[k * (PAD + 1) + b];
        totals[b] = s;
    }
    __syncthreads();
    if (b == 0) {
        int acc = 0;
        for (int v = 0; v <= PAD; ++v) { int c = totals[v]; totals[v] = acc; acc += c; }
    }
    __syncthreads();
    if (b <= PAD) {
        int acc = totals[b];
        for (int k = 0; k < SB; ++k) {
            int c = part[k * (PAD + 1) + b];
            part[k * (PAD + 1) + b] = acc;
            acc += c;
        }
    }
}

__global__ __launch_bounds__(256) void sort_scatter(const int* __restrict__ deg,
                                                    const int* __restrict__ part,
                                                    int* __restrict__ order) {
    __shared__ int cur[PAD + 1];
    int b = blockIdx.x, tid = threadIdx.x;
    if (tid <= PAD) cur[tid] = part[b * (PAD + 1) + tid];
    __syncthreads();
    int i0 = b * SCH, i1 = min(i0 + SCH, NA);
    for (int i = i0 + tid; i < i1; i += 256) {
        int p = atomicAdd(&cur[min(deg[i], PAD)], 1);
        order[p] = i;
    }
}

// ---------------- one-launch weight prep: f32 [K][N] -> f16 B^T [N][K] (+ padded iw1) ----------------

__global__ void prep_weights(const float* __restrict__ il1, const float* __restrict__ il2w,
                             const float* __restrict__ ilw, const float* __restrict__ iw2,
                             const float* __restrict__ l1w, const float* __restrict__ l2w,
                             const float* __restrict__ iw1,
                             unsigned short* __restrict__ il1t, unsigned short* __restrict__ il2wt,
                             unsigned short* __restrict__ ilwt, unsigned short* __restrict__ iw2t,
                             unsigned short* __restrict__ l1wt, unsigned short* __restrict__ l2wt,
                             unsigned short* __restrict__ iw1t) {
    int m = blockIdx.y;
    int e = blockIdx.x * 256 + threadIdx.x;
    if (m < 26) {
        const float* src; unsigned short* dst;
        if (m < 6)       { src = il1  + (size_t)m * 16384;        dst = il1t  + (size_t)m * 16384; }
        else if (m < 12) { src = il2w + (size_t)(m - 6) * 16384;  dst = il2wt + (size_t)(m - 6) * 16384; }
        else if (m < 18) { src = ilw  + (size_t)(m - 12) * 16384; dst = ilwt  + (size_t)(m - 12) * 16384; }
        else if (m < 24) { src = iw2  + (size_t)(m - 18) * 16384; dst = iw2t  + (size_t)(m - 18) * 16384; }
        else if (m == 24){ src = l1w; dst = l1wt; }
        else             { src = l2w; dst = l2wt; }
        int n = e >> 7, k = e & 127;
        dst[e] = f2h(src[k * 128 + n]);
    } else {
        int l = m - 26;
        if (e < 8192) {
            int n = e >> 6, k = e & 63;
            float v = (k < G) ? iw1[(size_t)l * G * H + k * H + n] : 0.0f;
            iw1t[(size_t)l * 8192 + e] = f2h(v);
        }
    }
}

// ---------------- filter tables via MFMA: grid (TBL/64, L); writes rows 1..TBL ----------------

__global__ __launch_bounds__(256) void table_gemm(const unsigned short* __restrict__ iw1t,
                                                  const float* __restrict__ ib1,
                                                  const unsigned short* __restrict__ iw2t,
                                                  const float* __restrict__ ib2,
                                                  unsigned short* __restrict__ wtab) {
    __shared__ unsigned short Bs[16384];      // 32 KB
    __shared__ _Float16 Ts[64 * 136];         // 17 KB: ea staging, then t
    int l = blockIdx.y;
    int tid = threadIdx.x;
    int w = tid >> 6, lane = tid & 63, lr = lane & 15, lq = lane >> 4;
    int r0 = blockIdx.x * 64;
    int trow = w * 16;
    const float step  = DMAX / (float)(TBL - 1);
    const float sp    = 5.0f / 49.0f;
    const float coeff = -0.5f / (sp * sp);

    if (blockIdx.x == 0 && tid < H)
        wtab[(size_t)l * TSTR + tid] = 0;      // zero row 0

    for (int i = tid; i < 1024; i += 256) {
        int row = i >> 3, g = i & 7;
        int gs = (g ^ row) & 7;
        *(uint4*)&Bs[row * 64 + gs * 8] = *(const uint4*)&iw1t[(size_t)l * 8192 + i * 8];
    }
    for (int i = tid; i < 64 * 64; i += 256) {
        int r = i >> 6, g = i & 63;
        float d = (float)(r0 + r) * step;
        float dd = d - (float)g * sp;
        Ts[r * 136 + g] = (_Float16)((g < G) ? __expf(coeff * dd * dd) : 0.0f);
    }
    float Cj[4];
    #pragma unroll
    for (int j = 0; j < 4; ++j) {
        float d = (float)(r0 + trow + 4 * lq + j) * step;
        Cj[j] = 0.5f * (cosf(d * (3.14159265358979323846f / 5.0f)) + 1.0f);
    }
    __syncthreads();
    half8 af[2];
    #pragma unroll
    for (int ks = 0; ks < 2; ++ks)
        af[ks] = *(const half8*)&Ts[(trow + lr) * 136 + ks * 32 + lq * 8];
    __syncthreads();

    #pragma unroll
    for (int n = 0; n < 8; ++n) {
        f32x4 acc = {0.f, 0.f, 0.f, 0.f};
        #pragma unroll
        for (int ks = 0; ks < 2; ++ks) {
            int row = n * 16 + lr, g = ks * 4 + lq;
            half8 bf = *(const half8*)&Bs[row * 64 + ((g ^ row) & 7) * 8];
            acc = __builtin_amdgcn_mfma_f32_16x16x32_f16(af[ks], bf, acc, 0, 0, 0);
        }
        float b = ib1[l * H + n * 16 + lr];
        #pragma unroll
        for (int j = 0; j < 4; ++j)
            Ts[(trow + 4 * lq + j) * 136 + n * 16 + lr] = (_Float16)sspf(acc[j] + b);
    }
    __syncthreads();
    for (int i = tid; i < 2048; i += 256) {
        int row = i >> 4, g = i & 15;
        *(uint4*)&Bs[bofs(row, g)] = *(const uint4*)&iw2t[(size_t)l * 16384 + i * 8];
    }
    half8 tf[4];
    #pragma unroll
    for (int ks = 0; ks < 4; ++ks)
        tf[ks] = *(const half8*)&Ts[(trow + lr) * 136 + ks * 32 + lq * 8];
    __syncthreads();
    #pragma unroll
    for (int n = 0; n < 8; ++n) {
        f32x4 acc = {0.f, 0.f, 0.f, 0.f};
        #pragma unroll
        for (int ks = 0; ks < 4; ++ks) {
            half8 bf = *(const half8*)&Bs[bofs(n * 16 + lr, ks * 4 + lq)];
            acc = __builtin_amdgcn_mfma_f32_16x16x32_f16(tf[ks], bf, acc, 0, 0, 0);
        }
        float b = ib2[l * H + n * 16 + lr];
        #pragma unroll
        for (int j = 0; j < 4; ++j) {
            int row = r0 + trow + 4 * lq + j;
            wtab[(size_t)l * TSTR + (size_t)(row + 1) * H + n * 16 + lr] =
                f2h((acc[j] + b) * Cj[j]);
        }
    }
}

// ---------------- fused h-init (f16) + x = f16(emb[z] @ B)  (layer 0) ----------------

__global__ __launch_bounds__(256) void gemm_hx(const int* __restrict__ z,
                                               const float* __restrict__ emb,
                                               const unsigned short* __restrict__ Bt,
                                               unsigned short* __restrict__ hout,
                                               unsigned short* __restrict__ xout, int M) {
    __shared__ unsigned short Bs[16384];
    int tid = threadIdx.x;
    int w = tid >> 6, lane = tid & 63, lr = lane & 15, lq = lane >> 4;
    int r0 = blockIdx.x * 64 + w * 16;
    for (int i = tid; i < 2048; i += 256) {
        int row = i >> 4, g = i & 15;
        *(uint4*)&Bs[bofs(row, g)] = *(const uint4*)&Bt[i * 8];
    }
    int row = min(r0 + lr, M - 1);
    const float* arow = emb + (size_t)z[row] * H;
    half8 af[4];
    #pragma unroll
    for (int ks = 0; ks < 4; ++ks) {
        float4 a = *(const float4*)(arow + ks * 32 + lq * 8);
        float4 b = *(const float4*)(arow + ks * 32 + lq * 8 + 4);
        af[ks] = cvt8(a, b);
        if (r0 + lr < M)
            *(half8*)&hout[(size_t)(r0 + lr) * H + ks * 32 + lq * 8] = af[ks];
    }
    __syncthreads();
    #pragma unroll
    for (int n = 0; n < 8; ++n) {
        f32x4 acc = {0.f, 0.f, 0.f, 0.f};
        #pragma unroll
        for (int ks = 0; ks < 4; ++ks) {
            half8 bf = *(const half8*)&Bs[bofs(n * 16 + lr, ks * 4 + lq)];
            acc = __builtin_amdgcn_mfma_f32_16x16x32_f16(af[ks], bf, acc, 0, 0, 0);
        }
        #pragma unroll
        for (int j = 0; j < 4; ++j) {
            int orow = r0 + 4 * lq + j;
            if (orow < M) xout[(size_t)orow * H + n * 16 + lr] = f2h(acc[j]);
        }
    }
}

// ---------------- fused node update: 512 threads, 128 rows/block, 64 KB LDS ----------------
// ALL Ts-producing passes use SWAPPED mfma(bf, ?) -> lane holds C[row=trow+lr][4 consecutive
// cols] -> vectorized half4 stores. Global hout16 write is done from Ts, fully coalesced.

template<int RES, int HASX, int FIN>
__global__ __launch_bounds__(512, 4) void node_fused(const unsigned short* __restrict__ Ain16,
                                                     const float* __restrict__ bias1,
                                                     const unsigned short* __restrict__ B1t,
                                                     const unsigned short* __restrict__ hres16,
                                                     unsigned short* __restrict__ hout16,
                                                     float* __restrict__ houtf,
                                                     const float* __restrict__ bias2,
                                                     const unsigned short* __restrict__ B2t,
                                                     const unsigned short* __restrict__ B3t,
                                                     const float* __restrict__ bias3,
                                                     const unsigned short* __restrict__ B4t,
                                                     const float* __restrict__ bias4,
                                                     unsigned short* __restrict__ xout, int M) {
    __shared__ unsigned short Bs[16384];   // 32 KB
    __shared__ _Float16 Ts[128 * 128];     // 32 KB, 8B-granule swizzle via off8()
    int tid = threadIdx.x;
    int w = tid >> 6, lane = tid & 63, lr = lane & 15, lq = lane >> 4;
    int r0 = blockIdx.x * 128 + w * 16;
    int trow = w * 16;

    for (int i = tid; i < 2048; i += 512) {
        int row = i >> 4, g = i & 15;
        *(uint4*)&Bs[bofs(row, g)] = *(const uint4*)&B1t[i * 8];
    }
    half8 af[4];
    {
        const unsigned short* arow = Ain16 + (size_t)min(r0 + lr, M - 1) * H;
        #pragma unroll
        for (int ks = 0; ks < 4; ++ks)
            af[ks] = *(const half8*)(arow + ks * 32 + lq * 8);
    }
    __syncthreads();

    // ---- pass A (SWAPPED): t = ssp(A @ B1 + b1) -> Ts ----
    #pragma unroll
    for (int n = 0; n < 8; ++n) {
        f32x4 acc = {0.f, 0.f, 0.f, 0.f};
        #pragma unroll
        for (int ks = 0; ks < 4; ++ks) {
            half8 bf = *(const half8*)&Bs[bofs(n * 16 + lr, ks * 4 + lq)];
            acc = __builtin_amdgcn_mfma_f32_16x16x32_f16(bf, af[ks], acc, 0, 0, 0);
        }
        float4 b4 = *(const float4*)&bias1[n * 16 + (lq << 2)];
        half4 o;
        o[0] = (_Float16)sspf(acc[0] + b4.x);
        o[1] = (_Float16)sspf(acc[1] + b4.y);
        o[2] = (_Float16)sspf(acc[2] + b4.z);
        o[3] = (_Float16)sspf(acc[3] + b4.w);
        *(half4*)&Ts[off8(trow + lr, (n << 2) + lq)] = o;
    }
    __syncthreads();
    for (int i = tid; i < 2048; i += 512) {
        int row = i >> 4, g = i & 15;
        *(uint4*)&Bs[bofs(row, g)] = *(const uint4*)&B2t[i * 8];
    }
    half8 tf[4];
    #pragma unroll
    for (int ks = 0; ks < 4; ++ks)
        tf[ks] = ts_read(Ts, trow + lr, ks * 32 + lq * 8);
    __syncthreads();

    // ---- pass B (SWAPPED): v = h + t @ B2 + b2 -> Ts ----
    #pragma unroll
    for (int n = 0; n < 8; ++n) {
        f32x4 acc = {0.f, 0.f, 0.f, 0.f};
        #pragma unroll
        for (int ks = 0; ks < 4; ++ks) {
            half8 bf = *(const half8*)&Bs[bofs(n * 16 + lr, ks * 4 + lq)];
            acc = __builtin_amdgcn_mfma_f32_16x16x32_f16(bf, tf[ks], acc, 0, 0, 0);
        }
        float4 b4 = *(const float4*)&bias2[n * 16 + (lq << 2)];
        half4 o;
        if (RES) {
            half4 hr = *(const half4*)&hres16[(size_t)min(r0 + lr, M - 1) * H + n * 16 + (lq << 2)];
            o[0] = (_Float16)(acc[0] + b4.x + (float)hr[0]);
            o[1] = (_Float16)(acc[1] + b4.y + (float)hr[1]);
            o[2] = (_Float16)(acc[2] + b4.z + (float)hr[2]);
            o[3] = (_Float16)(acc[3] + b4.w + (float)hr[3]);
        } else {
            o[0] = (_Float16)(acc[0] + b4.x);
            o[1] = (_Float16)(acc[1] + b4.y);
            o[2] = (_Float16)(acc[2] + b4.z);
            o[3] = (_Float16)(acc[3] + b4.w);
        }
        *(half4*)&Ts[off8(trow + lr, (n << 2) + lq)] = o;
    }
    __syncthreads();

    if (!FIN) {
        // coalesced hout16 write from Ts (thread -> row tid>>2, 64B) + stage B3
        if (HASX) {
            for (int i = tid; i < 2048; i += 512) {
                int row = i >> 4, g = i & 15;
                *(uint4*)&Bs[bofs(row, g)] = *(const uint4*)&B3t[i * 8];
            }
        }
        {
            int row = tid >> 2, c0 = (tid & 3) << 5;
            int grow = blockIdx.x * 128 + row;
            if (grow < M) {
                #pragma unroll
                for (int q = 0; q < 4; ++q) {
                    half8 v = ts_read(Ts, row, c0 + q * 8);
                    *(half8*)&hout16[(size_t)grow * H + c0 + q * 8] = v;
                }
            }
        }
        if (HASX) {
            half8 hf[4];
            #pragma unroll
            for (int ks = 0; ks < 4; ++ks)
                hf[ks] = ts_read(Ts, trow + lr, ks * 32 + lq * 8);
            __syncthreads();
            #pragma unroll
            for (int n = 0; n < 8; ++n) {
                f32x4 acc = {0.f, 0.f, 0.f, 0.f};
                #pragma unroll
                for (int ks = 0; ks < 4; ++ks) {
                    half8 bf = *(const half8*)&Bs[bofs(n * 16 + lr, ks * 4 + lq)];
                    acc = __builtin_amdgcn_mfma_f32_16x16x32_f16(hf[ks], bf, acc, 0, 0, 0);
                }
                #pragma unroll
                for (int j = 0; j < 4; ++j) {
                    int row = r0 + 4 * lq + j;
                    if (row < M) xout[(size_t)row * H + n * 16 + lr] = f2h(acc[j]);
                }
            }
        }
    } else {
        // ---- FIN: pass C' (SWAPPED ssp(v@B3+b3) -> Ts) then pass D (normal, u@B4+b4 -> f32) ----
        for (int i = tid; i < 2048; i += 512) {
            int row = i >> 4, g = i & 15;
            *(uint4*)&Bs[bofs(row, g)] = *(const uint4*)&B3t[i * 8];
        }
        half8 vf[4];
        #pragma unroll
        for (int ks = 0; ks < 4; ++ks)
            vf[ks] = ts_read(Ts, trow + lr, ks * 32 + lq * 8);
        __syncthreads();
        #pragma unroll
        for (int n = 0; n < 8; ++n) {
            f32x4 acc = {0.f, 0.f, 0.f, 0.f};
            #pragma unroll
            for (int ks = 0; ks < 4; ++ks) {
                half8 bf = *(const half8*)&Bs[bofs(n * 16 + lr, ks * 4 + lq)];
                acc = __builtin_amdgcn_mfma_f32_16x16x32_f16(bf, vf[ks], acc, 0, 0, 0);
            }
            float4 b4 = *(const float4*)&bias3[n * 16 + (lq << 2)];
            half4 o;
            o[0] = (_Float16)sspf(acc[0] + b4.x);
            o[1] = (_Float16)sspf(acc[1] + b4.y);
            o[2] = (_Float16)sspf(acc[2] + b4.z);
            o[3] = (_Float16)sspf(acc[3] + b4.w);
            *(half4*)&Ts[off8(trow + lr, (n << 2) + lq)] = o;
        }
        __syncthreads();
        for (int i = tid; i < 2048; i += 512) {
            int row = i >> 4, g = i & 15;
            *(uint4*)&Bs[bofs(row, g)] = *(const uint4*)&B4t[i * 8];
        }
        half8 uf[4];
        #pragma unroll
        for (int ks = 0; ks < 4; ++ks)
            uf[ks] = ts_read(Ts, trow + lr, ks * 32 + lq * 8);
        __syncthreads();
        #pragma unroll
        for (int n = 0; n < 8; ++n) {
            f32x4 acc = {0.f, 0.f, 0.f, 0.f};
            #pragma unroll
            for (int ks = 0; ks < 4; ++ks) {
                half8 bf = *(const half8*)&Bs[bofs(n * 16 + lr, ks * 4 + lq)];
                acc = __builtin_amdgcn_mfma_f32_16x16x32_f16(uf[ks], bf, acc, 0, 0, 0);
            }
            float b = bias4[n * 16 + lr];
            #pragma unroll
            for (int j = 0; j < 4; ++j) {
                int row = r0 + 4 * lq + j;
                if (row < M) houtf[(size_t)row * H + n * 16 + lr] = acc[j] + b;
            }
        }
    }
}

// ---------------- edge aggregation: degree-sorted + dispatch-interleaved ----------------

__global__ __launch_bounds__(256) void edge_agg(const int* __restrict__ deg,
                                                const int* __restrict__ order,
                                                const unsigned* __restrict__ meta,
                                                const unsigned short* __restrict__ x,
                                                const unsigned short* __restrict__ wt,
                                                unsigned short* __restrict__ agg) {
    int wv = threadIdx.x >> 6, ln = threadIdx.x & 63;
    int a = ln >> 4, fl = ln & 15;
    int gw = (blockIdx.x << 2) + wv;               // 12500 waves (NA=50000, 4 atoms/wave)
    int chunk = (gw % 250) * 50 + (gw / 250);      // bijective interleave over 12500 chunks
    int pos = (chunk << 2) + a;
    int i = order[pos];
    int n8 = (min(deg[i], PAD) + 7) & ~7;
    const unsigned* mrow = meta + (size_t)i * PAD;
    int f8 = fl << 3;
    float acc[8] = {};
    for (int p = 0; p < n8; p += 8) {
        unsigned mm[8];
        #pragma unroll
        for (int j = 0; j < 8; ++j) mm[j] = mrow[p + j];
        uint4 xv[8], wv8[8];
        #pragma unroll
        for (int j = 0; j < 8; ++j) {
            unsigned s = mm[j] & 0xFFFFu, idx = mm[j] >> 16;
            xv[j]  = *(const uint4*)(x  + ((size_t)s   << 7) + f8);
            wv8[j] = *(const uint4*)(wt + ((size_t)idx << 7) + f8);
        }
        #pragma unroll
        for (int j = 0; j < 8; ++j) {
            acc[0] += hlo(xv[j].x) * hlo(wv8[j].x);
            acc[1] += hhi(xv[j].x) * hhi(wv8[j].x);
            acc[2] += hlo(xv[j].y) * hlo(wv8[j].y);
            acc[3] += hhi(xv[j].y) * hhi(wv8[j].y);
            acc[4] += hlo(xv[j].z) * hlo(wv8[j].z);
            acc[5] += hhi(xv[j].z) * hhi(wv8[j].z);
            acc[6] += hlo(xv[j].w) * hlo(wv8[j].w);
            acc[7] += hhi(xv[j].w) * hhi(wv8[j].w);
        }
    }
    uint4 ov;
    ov.x = (unsigned)f2h(acc[0]) | ((unsigned)f2h(acc[1]) << 16);
    ov.y = (unsigned)f2h(acc[2]) | ((unsigned)f2h(acc[3]) << 16);
    ov.z = (unsigned)f2h(acc[4]) | ((unsigned)f2h(acc[5]) << 16);
    ov.w = (unsigned)f2h(acc[6]) | ((unsigned)f2h(acc[7]) << 16);
    *(uint4*)&agg[((size_t)i << 7) + f8] = ov;
}

// ---------------- readout ----------------

__global__ void mol_bounds(const int* __restrict__ a2c, const int* __restrict__ c2m,
                           int* __restrict__ ms, int* __restrict__ me) {
    int i = blockIdx.x * 256 + threadIdx.x;
    if (i >= NA) return;
    int m = c2m[a2c[i]];
    int mp = (i == 0) ? -1 : c2m[a2c[i - 1]];
    if (m != mp) ms[m] = i;
    int mn = (i == NA - 1) ? -1 : c2m[a2c[i + 1]];
    if (m != mn) me[m] = i + 1;
}

__global__ __launch_bounds__(512) void mol_sum(const int* __restrict__ ms, const int* __restrict__ me,
                                               const float* __restrict__ h2buf, float* __restrict__ mol) {
    __shared__ float red[4][128];
    int m = blockIdx.x;
    int f = threadIdx.x & 127, q = threadIdx.x >> 7;
    float acc = 0.f;
    int e0 = ms[m], e1 = me[m];
    for (int i = e0 + q; i < e1; i += 4) acc += h2buf[((size_t)i << 7) + f];
    red[q][f] = acc;
    __syncthreads();
    if (q == 0) mol[(m << 7) + f] = red[0][f] + red[1][f] + red[2][f] + red[3][f];
}

__global__ void final_mlp(const float* __restrict__ mol, const float* __restrict__ h1w,
                          const float* __restrict__ h1b, const float* __restrict__ h2w,
                          const float* __restrict__ h2b, float* __restrict__ out) {
    int m = blockIdx.x;
    int j = threadIdx.x;
    float acc = h1b[j];
    for (int k = 0; k < H; ++k) acc += mol[(m << 7) + k] * h1w[k * 64 + j];
    float hv = sspf(acc) * h2w[j];
    #pragma unroll
    for (int off = 32; off > 0; off >>= 1) hv += __shfl_down(hv, off);
    if (j == 0) out[m] = hv + h2b[0];
}

} // namespace

extern "C" void kernel_launch(void* const* d_in, const int* in_sizes, int n_in,
                              void* d_out, int out_size, void* d_ws, size_t ws_size,
                              hipStream_t stream) {
    const int*   z    = (const int*)d_in[0];
    const float* pos  = (const float*)d_in[1];
    const int*   ei   = (const int*)d_in[2];
    const int*   a2c  = (const int*)d_in[3];
    const int*   c2m  = (const int*)d_in[4];
    const float* emb  = (const float*)d_in[5];
    const float* iw1  = (const float*)d_in[6];
    const float* ib1  = (const float*)d_in[7];
    const float* iw2  = (const float*)d_in[8];
    const float* ib2  = (const float*)d_in[9];
    const float* il1  = (const float*)d_in[10];
    const float* il2w = (const float*)d_in[11];
    const float* il2b = (const float*)d_in[12];
    const float* ilw  = (const float*)d_in[13];
    const float* ilb  = (const float*)d_in[14];
    const float* l1w  = (const float*)d_in[15];
    const float* l1b  = (const float*)d_in[16];
    const float* l2w  = (const float*)d_in[17];
    const float* l2b  = (const float*)d_in[18];
    const float* h1w  = (const float*)d_in[19];
    const float* h1b  = (const float*)d_in[20];
    const float* h2w  = (const float*)d_in[21];
    const float* h2b  = (const float*)d_in[22];
    float* out = (float*)d_out;
    (void)in_sizes; (void)n_in; (void)out_size; (void)ws_size;

    char* base = (char*)d_ws;
    size_t off = 0;
    auto carve = [&](size_t bytes) -> char* {
        char* p = base + off;
        off += (bytes + 255) & ~(size_t)255;
        return p;
    };
    unsigned short* hb    = (unsigned short*)carve((size_t)NA * H * 2);
    unsigned short* xb    = (unsigned short*)carve((size_t)NA * H * 2);
    float*          agg   = (float*)carve((size_t)NA * H * 4);   // f16 during loop, f32 at end
    unsigned short* wtab  = (unsigned short*)carve((size_t)L * TSTR * 2);
    unsigned*       meta  = (unsigned*)carve(((size_t)NA * PAD + 16) * 4);
    int*            counts= (int*)carve((size_t)NA * 4);
    int*            order = (int*)carve((size_t)NA * 4);
    int*            part  = (int*)carve((size_t)SB * (PAD + 1) * 4);
    int*            ms    = (int*)carve((size_t)NM * 4);
    int*            me    = (int*)carve((size_t)NM * 4);
    float*          mol   = (float*)carve((size_t)NM * H * 4);
    unsigned short* il1t  = (unsigned short*)carve((size_t)L * H * H * 2);
    unsigned short* il2wt = (unsigned short*)carve((size_t)L * H * H * 2);
    unsigned short* ilwt  = (unsigned short*)carve((size_t)L * H * H * 2);
    unsigned short* iw2t  = (unsigned short*)carve((size_t)L * H * H * 2);
    unsigned short* l1wt  = (unsigned short*)carve((size_t)H * H * 2);
    unsigned short* l2wt  = (unsigned short*)carve((size_t)H * H * 2);
    unsigned short* iw1t  = (unsigned short*)carve((size_t)L * H * 64 * 2);
    unsigned short* aggh  = (unsigned short*)agg;

    hipMemsetAsync(counts, 0, (size_t)NA * 4, stream);
    hipMemsetAsync(meta, 0, ((size_t)NA * PAD + 16) * 4, stream);  // pad slots = (s=0, row 0 = zero)
    edge_build<<<(NE / 4 + 255) / 256, 256, 0, stream>>>(pos, ei, counts, meta);
    sort_hist<<<SB, 256, 0, stream>>>(counts, part);
    sort_scan<<<1, 128, 0, stream>>>(part);
    sort_scatter<<<SB, 256, 0, stream>>>(counts, part, order);

    prep_weights<<<dim3(64, 32), 256, 0, stream>>>(il1, il2w, ilw, iw2, l1w, l2w, iw1,
                                                   il1t, il2wt, ilwt, iw2t, l1wt, l2wt, iw1t);
    table_gemm<<<dim3(TBL / 64, L), 256, 0, stream>>>(iw1t, ib1, iw2t, ib2, wtab);

    const int NG  = (NA + 63) / 64;    // 782  (gemm_hx, 64 rows/block)
    const int NGn = (NA + 127) / 128;  // 391  (node_fused, 128 rows/block)
    gemm_hx<<<NG, 256, 0, stream>>>(z, emb, il1t, hb, xb, NA);
    for (int k = 0; k < L; ++k) {
        edge_agg<<<NA / 16, 256, 0, stream>>>(counts, order, meta, xb,
                                              wtab + (size_t)k * TSTR, aggh);
        if (k < L - 1) {
            node_fused<1, 1, 0><<<NGn, 512, 0, stream>>>(aggh,
                il2b + (size_t)k * H, il2wt + (size_t)k * H * H,
                hb, hb, nullptr, ilb + (size_t)k * H, ilwt + (size_t)k * H * H,
                il1t + (size_t)(k + 1) * H * H, nullptr, nullptr, nullptr, xb, NA);
        } else {
            // last layer fused with final ssp(h@l1w+l1b)@l2w+l2b -> agg (f32)
            node_fused<1, 0, 1><<<NGn, 512, 0, stream>>>(aggh,
                il2b + (size_t)k * H, il2wt + (size_t)k * H * H,
                hb, nullptr, agg, ilb + (size_t)k * H, ilwt + (size_t)k * H * H,
                l1wt, l1b, l2wt, l2b, nullptr, NA);
        }
    }

    hipMemsetAsync(ms, 0, (size_t)NM * 4, stream);
    hipMemsetAsync(me, 0, (size_t)NM * 4, stream);
    mol_bounds<<<(NA + 255) / 256, 256, 0, stream>>>(a2c, c2m, ms, me);
    mol_sum<<<NM, 512, 0, stream>>>(ms, me, agg, mol);
    final_mlp<<<NM, 64, 0, stream>>>(mol, h1w, h1b, h2w, h2b, out);
}

// Round 18
// 600.317 us; speedup vs baseline: 1.0127x; 1.0127x over previous
//
#include <hip/hip_runtime.h>
#include <math.h>

namespace {

constexpr int NA  = 50000;
constexpr int NE  = 1600000;
constexpr int NM  = 500;
constexpr int H   = 128;
constexpr int G   = 50;
constexpr int L   = 6;
constexpr int TBL = 8192;
constexpr int TSTR = (TBL + 1) * H;     // per-layer wtab stride; ROW 0 = zero row, data rows 1..TBL
constexpr int PAD = 80;
constexpr float DMAX = 5.6f;            // beyond 5.6 the Gaussian envelope is <3e-8; do NOT lower
                                        // (C(d) rises again past d=5 — round 9 lesson)
constexpr int SB  = 64;                 // sort blocks
constexpr int SCH = (NA + SB - 1) / SB; // 782 atoms per sort block

typedef _Float16 half8 __attribute__((ext_vector_type(8)));
typedef _Float16 half4 __attribute__((ext_vector_type(4)));
typedef float f32x4 __attribute__((ext_vector_type(4)));
struct hpair { _Float16 x, y; };

__device__ __forceinline__ float sspf(float v) {
    // softplus(v) - ln2 via native exp/log
    return fmaxf(v, 0.0f) + __logf(1.0f + __expf(-fabsf(v))) - 0.6931471805599453f;
}
__device__ __forceinline__ unsigned short f2h(float f) {
    _Float16 h = (_Float16)f;
    return __builtin_bit_cast(unsigned short, h);
}
__device__ __forceinline__ half8 cvt8(float4 a, float4 b) {
    half8 r;
    r[0] = (_Float16)a.x; r[1] = (_Float16)a.y; r[2] = (_Float16)a.z; r[3] = (_Float16)a.w;
    r[4] = (_Float16)b.x; r[5] = (_Float16)b.y; r[6] = (_Float16)b.z; r[7] = (_Float16)b.w;
    return r;
}
__device__ __forceinline__ float hlo(unsigned v) {
    return (float)__builtin_bit_cast(hpair, v).x;
}
__device__ __forceinline__ float hhi(unsigned v) {
    return (float)__builtin_bit_cast(hpair, v).y;
}
// B^T LDS granule offset with XOR swizzle for 128-u16 row pitch (16B granules)
__device__ __forceinline__ int bofs(int nrow, int g) {   // g = 16B granule 0..15
    int gs = (g & 8) | ((g ^ nrow) & 7);
    return nrow * 128 + gs * 8;
}
// Ts f16 [128][128], swizzled on 8B granules (4 f16); ~2-way bank access (free per m136)
__device__ __forceinline__ int off8(int row, int g) {   // g = col>>2, 0..31
    int gs = (g & 24) | ((g ^ row) & 7);
    return (row << 7) + (gs << 2);
}
__device__ __forceinline__ half8 ts_read(const _Float16* Ts, int row, int col0) {
    int g0 = col0 >> 2;
    half4 a = *(const half4*)&Ts[off8(row, g0)];
    half4 b = *(const half4*)&Ts[off8(row, g0 + 1)];
    half8 r;
    r[0] = a[0]; r[1] = a[1]; r[2] = a[2]; r[3] = a[3];
    r[4] = b[0]; r[5] = b[1]; r[6] = b[2]; r[7] = b[3];
    return r;
}

// ---------------- preprocessing: one-pass padded-CSR build (1 edge/thread; r17's
// 4-edge batching cut queued waves 4x and regressed — TLP beats ILP for atomic+scatter) ----

__global__ void edge_build(const float* __restrict__ pos, const int* __restrict__ ei,
                           int* __restrict__ counts, unsigned* __restrict__ meta) {
    int e = blockIdx.x * 256 + threadIdx.x;
    if (e >= NE) return;
    int s = ei[e], t = ei[NE + e];
    float dx = pos[3*s]   - pos[3*t];
    float dy = pos[3*s+1] - pos[3*t+1];
    float dz = pos[3*s+2] - pos[3*t+2];
    float d = sqrtf(dx*dx + dy*dy + dz*dz + 1e-12f);
    float u = d * ((float)(TBL - 1) / DMAX);
    if (u < (float)(TBL - 1)) {
        int idx = (int)(u + 0.5f) + 1;           // rows 1..TBL (row 0 = zero row)
        int r = atomicAdd(&counts[t], 1);
        if (r < PAD) meta[(size_t)t * PAD + r] = (unsigned)s | ((unsigned)idx << 16);
    }
}

// ---------------- parallel counting sort (64 blocks, LDS atomics) ----------------

__global__ __launch_bounds__(256) void sort_hist(const int* __restrict__ deg,
                                                 int* __restrict__ part) {
    __shared__ int bins[PAD + 1];
    int b = blockIdx.x, tid = threadIdx.x;
    if (tid <= PAD) bins[tid] = 0;
    __syncthreads();
    int i0 = b * SCH, i1 = min(i0 + SCH, NA);
    for (int i = i0 + tid; i < i1; i += 256)
        atomicAdd(&bins[min(deg[i], PAD)], 1);
    __syncthreads();
    if (tid <= PAD) part[b * (PAD + 1) + tid] = bins[tid];
}

__global__ __launch_bounds__(128) void sort_scan(int* __restrict__ part) {
    __shared__ int totals[PAD + 1];
    int b = threadIdx.x;
    if (b <= PAD) {
        int s = 0;
        for (int k = 0; k < SB; ++k) s += part[k * (PAD + 1) + b];
        totals[b] = s;
    }
    __syncthreads();
    if (b == 0) {
        int acc = 0;
        for (int v = 0; v <= PAD; ++v) { int c = totals[v]; totals[v] = acc; acc += c; }
    }
    __syncthreads();
    if (b <= PAD) {
        int acc = totals[b];
        for (int k = 0; k < SB; ++k) {
            int c = part[k * (PAD + 1) + b];
            part[k * (PAD + 1) + b] = acc;
            acc += c;
        }
    }
}

__global__ __launch_bounds__(256) void sort_scatter(const int* __restrict__ deg,
                                                    const int* __restrict__ part,
                                                    int* __restrict__ order) {
    __shared__ int cur[PAD + 1];
    int b = blockIdx.x, tid = threadIdx.x;
    if (tid <= PAD) cur[tid] = part[b * (PAD + 1) + tid];
    __syncthreads();
    int i0 = b * SCH, i1 = min(i0 + SCH, NA);
    for (int i = i0 + tid; i < i1; i += 256) {
        int p = atomicAdd(&cur[min(deg[i], PAD)], 1);
        order[p] = i;
    }
}

// ---------------- one-launch weight prep: f32 [K][N] -> f16 B^T [N][K] (+ padded iw1) ----------------

__global__ void prep_weights(const float* __restrict__ il1, const float* __restrict__ il2w,
                             const float* __restrict__ ilw, const float* __restrict__ iw2,
                             const float* __restrict__ l1w, const float* __restrict__ l2w,
                             const float* __restrict__ iw1,
                             unsigned short* __restrict__ il1t, unsigned short* __restrict__ il2wt,
                             unsigned short* __restrict__ ilwt, unsigned short* __restrict__ iw2t,
                             unsigned short* __restrict__ l1wt, unsigned short* __restrict__ l2wt,
                             unsigned short* __restrict__ iw1t) {
    int m = blockIdx.y;
    int e = blockIdx.x * 256 + threadIdx.x;
    if (m < 26) {
        const float* src; unsigned short* dst;
        if (m < 6)       { src = il1  + (size_t)m * 16384;        dst = il1t  + (size_t)m * 16384; }
        else if (m < 12) { src = il2w + (size_t)(m - 6) * 16384;  dst = il2wt + (size_t)(m - 6) * 16384; }
        else if (m < 18) { src = ilw  + (size_t)(m - 12) * 16384; dst = ilwt  + (size_t)(m - 12) * 16384; }
        else if (m < 24) { src = iw2  + (size_t)(m - 18) * 16384; dst = iw2t  + (size_t)(m - 18) * 16384; }
        else if (m == 24){ src = l1w; dst = l1wt; }
        else             { src = l2w; dst = l2wt; }
        int n = e >> 7, k = e & 127;
        dst[e] = f2h(src[k * 128 + n]);
    } else {
        int l = m - 26;
        if (e < 8192) {
            int n = e >> 6, k = e & 63;
            float v = (k < G) ? iw1[(size_t)l * G * H + k * H + n] : 0.0f;
            iw1t[(size_t)l * 8192 + e] = f2h(v);
        }
    }
}

// ---------------- filter tables via MFMA: grid (TBL/64, L); writes rows 1..TBL ----------------

__global__ __launch_bounds__(256) void table_gemm(const unsigned short* __restrict__ iw1t,
                                                  const float* __restrict__ ib1,
                                                  const unsigned short* __restrict__ iw2t,
                                                  const float* __restrict__ ib2,
                                                  unsigned short* __restrict__ wtab) {
    __shared__ unsigned short Bs[16384];      // 32 KB
    __shared__ _Float16 Ts[64 * 136];         // 17 KB: ea staging, then t
    int l = blockIdx.y;
    int tid = threadIdx.x;
    int w = tid >> 6, lane = tid & 63, lr = lane & 15, lq = lane >> 4;
    int r0 = blockIdx.x * 64;
    int trow = w * 16;
    const float step  = DMAX / (float)(TBL - 1);
    const float sp    = 5.0f / 49.0f;
    const float coeff = -0.5f / (sp * sp);

    if (blockIdx.x == 0 && tid < H)
        wtab[(size_t)l * TSTR + tid] = 0;      // zero row 0

    for (int i = tid; i < 1024; i += 256) {
        int row = i >> 3, g = i & 7;
        int gs = (g ^ row) & 7;
        *(uint4*)&Bs[row * 64 + gs * 8] = *(const uint4*)&iw1t[(size_t)l * 8192 + i * 8];
    }
    for (int i = tid; i < 64 * 64; i += 256) {
        int r = i >> 6, g = i & 63;
        float d = (float)(r0 + r) * step;
        float dd = d - (float)g * sp;
        Ts[r * 136 + g] = (_Float16)((g < G) ? __expf(coeff * dd * dd) : 0.0f);
    }
    float Cj[4];
    #pragma unroll
    for (int j = 0; j < 4; ++j) {
        float d = (float)(r0 + trow + 4 * lq + j) * step;
        Cj[j] = 0.5f * (cosf(d * (3.14159265358979323846f / 5.0f)) + 1.0f);
    }
    __syncthreads();
    half8 af[2];
    #pragma unroll
    for (int ks = 0; ks < 2; ++ks)
        af[ks] = *(const half8*)&Ts[(trow + lr) * 136 + ks * 32 + lq * 8];
    __syncthreads();

    #pragma unroll
    for (int n = 0; n < 8; ++n) {
        f32x4 acc = {0.f, 0.f, 0.f, 0.f};
        #pragma unroll
        for (int ks = 0; ks < 2; ++ks) {
            int row = n * 16 + lr, g = ks * 4 + lq;
            half8 bf = *(const half8*)&Bs[row * 64 + ((g ^ row) & 7) * 8];
            acc = __builtin_amdgcn_mfma_f32_16x16x32_f16(af[ks], bf, acc, 0, 0, 0);
        }
        float b = ib1[l * H + n * 16 + lr];
        #pragma unroll
        for (int j = 0; j < 4; ++j)
            Ts[(trow + 4 * lq + j) * 136 + n * 16 + lr] = (_Float16)sspf(acc[j] + b);
    }
    __syncthreads();
    for (int i = tid; i < 2048; i += 256) {
        int row = i >> 4, g = i & 15;
        *(uint4*)&Bs[bofs(row, g)] = *(const uint4*)&iw2t[(size_t)l * 16384 + i * 8];
    }
    half8 tf[4];
    #pragma unroll
    for (int ks = 0; ks < 4; ++ks)
        tf[ks] = *(const half8*)&Ts[(trow + lr) * 136 + ks * 32 + lq * 8];
    __syncthreads();
    #pragma unroll
    for (int n = 0; n < 8; ++n) {
        f32x4 acc = {0.f, 0.f, 0.f, 0.f};
        #pragma unroll
        for (int ks = 0; ks < 4; ++ks) {
            half8 bf = *(const half8*)&Bs[bofs(n * 16 + lr, ks * 4 + lq)];
            acc = __builtin_amdgcn_mfma_f32_16x16x32_f16(tf[ks], bf, acc, 0, 0, 0);
        }
        float b = ib2[l * H + n * 16 + lr];
        #pragma unroll
        for (int j = 0; j < 4; ++j) {
            int row = r0 + trow + 4 * lq + j;
            wtab[(size_t)l * TSTR + (size_t)(row + 1) * H + n * 16 + lr] =
                f2h((acc[j] + b) * Cj[j]);
        }
    }
}

// ---------------- fused h-init (f16) + x = f16(emb[z] @ B)  (layer 0) ----------------

__global__ __launch_bounds__(256) void gemm_hx(const int* __restrict__ z,
                                               const float* __restrict__ emb,
                                               const unsigned short* __restrict__ Bt,
                                               unsigned short* __restrict__ hout,
                                               unsigned short* __restrict__ xout, int M) {
    __shared__ unsigned short Bs[16384];
    int tid = threadIdx.x;
    int w = tid >> 6, lane = tid & 63, lr = lane & 15, lq = lane >> 4;
    int r0 = blockIdx.x * 64 + w * 16;
    for (int i = tid; i < 2048; i += 256) {
        int row = i >> 4, g = i & 15;
        *(uint4*)&Bs[bofs(row, g)] = *(const uint4*)&Bt[i * 8];
    }
    int row = min(r0 + lr, M - 1);
    const float* arow = emb + (size_t)z[row] * H;
    half8 af[4];
    #pragma unroll
    for (int ks = 0; ks < 4; ++ks) {
        float4 a = *(const float4*)(arow + ks * 32 + lq * 8);
        float4 b = *(const float4*)(arow + ks * 32 + lq * 8 + 4);
        af[ks] = cvt8(a, b);
        if (r0 + lr < M)
            *(half8*)&hout[(size_t)(r0 + lr) * H + ks * 32 + lq * 8] = af[ks];
    }
    __syncthreads();
    #pragma unroll
    for (int n = 0; n < 8; ++n) {
        f32x4 acc = {0.f, 0.f, 0.f, 0.f};
        #pragma unroll
        for (int ks = 0; ks < 4; ++ks) {
            half8 bf = *(const half8*)&Bs[bofs(n * 16 + lr, ks * 4 + lq)];
            acc = __builtin_amdgcn_mfma_f32_16x16x32_f16(af[ks], bf, acc, 0, 0, 0);
        }
        #pragma unroll
        for (int j = 0; j < 4; ++j) {
            int orow = r0 + 4 * lq + j;
            if (orow < M) xout[(size_t)orow * H + n * 16 + lr] = f2h(acc[j]);
        }
    }
}

// ---------------- fused node update: 512 threads, 128 rows/block, 64 KB LDS ----------------
// ALL Ts-producing passes use SWAPPED mfma(bf, ?) -> lane holds C[row=trow+lr][4 consecutive
// cols] -> vectorized half4 stores. Global hout16 write is done from Ts, fully coalesced.

template<int RES, int HASX, int FIN>
__global__ __launch_bounds__(512, 4) void node_fused(const unsigned short* __restrict__ Ain16,
                                                     const float* __restrict__ bias1,
                                                     const unsigned short* __restrict__ B1t,
                                                     const unsigned short* __restrict__ hres16,
                                                     unsigned short* __restrict__ hout16,
                                                     float* __restrict__ houtf,
                                                     const float* __restrict__ bias2,
                                                     const unsigned short* __restrict__ B2t,
                                                     const unsigned short* __restrict__ B3t,
                                                     const float* __restrict__ bias3,
                                                     const unsigned short* __restrict__ B4t,
                                                     const float* __restrict__ bias4,
                                                     unsigned short* __restrict__ xout, int M) {
    __shared__ unsigned short Bs[16384];   // 32 KB
    __shared__ _Float16 Ts[128 * 128];     // 32 KB, 8B-granule swizzle via off8()
    int tid = threadIdx.x;
    int w = tid >> 6, lane = tid & 63, lr = lane & 15, lq = lane >> 4;
    int r0 = blockIdx.x * 128 + w * 16;
    int trow = w * 16;

    for (int i = tid; i < 2048; i += 512) {
        int row = i >> 4, g = i & 15;
        *(uint4*)&Bs[bofs(row, g)] = *(const uint4*)&B1t[i * 8];
    }
    half8 af[4];
    {
        const unsigned short* arow = Ain16 + (size_t)min(r0 + lr, M - 1) * H;
        #pragma unroll
        for (int ks = 0; ks < 4; ++ks)
            af[ks] = *(const half8*)(arow + ks * 32 + lq * 8);
    }
    __syncthreads();

    // ---- pass A (SWAPPED): t = ssp(A @ B1 + b1) -> Ts ----
    #pragma unroll
    for (int n = 0; n < 8; ++n) {
        f32x4 acc = {0.f, 0.f, 0.f, 0.f};
        #pragma unroll
        for (int ks = 0; ks < 4; ++ks) {
            half8 bf = *(const half8*)&Bs[bofs(n * 16 + lr, ks * 4 + lq)];
            acc = __builtin_amdgcn_mfma_f32_16x16x32_f16(bf, af[ks], acc, 0, 0, 0);
        }
        float4 b4 = *(const float4*)&bias1[n * 16 + (lq << 2)];
        half4 o;
        o[0] = (_Float16)sspf(acc[0] + b4.x);
        o[1] = (_Float16)sspf(acc[1] + b4.y);
        o[2] = (_Float16)sspf(acc[2] + b4.z);
        o[3] = (_Float16)sspf(acc[3] + b4.w);
        *(half4*)&Ts[off8(trow + lr, (n << 2) + lq)] = o;
    }
    __syncthreads();
    for (int i = tid; i < 2048; i += 512) {
        int row = i >> 4, g = i & 15;
        *(uint4*)&Bs[bofs(row, g)] = *(const uint4*)&B2t[i * 8];
    }
    half8 tf[4];
    #pragma unroll
    for (int ks = 0; ks < 4; ++ks)
        tf[ks] = ts_read(Ts, trow + lr, ks * 32 + lq * 8);
    __syncthreads();

    // ---- pass B (SWAPPED): v = h + t @ B2 + b2 -> Ts ----
    #pragma unroll
    for (int n = 0; n < 8; ++n) {
        f32x4 acc = {0.f, 0.f, 0.f, 0.f};
        #pragma unroll
        for (int ks = 0; ks < 4; ++ks) {
            half8 bf = *(const half8*)&Bs[bofs(n * 16 + lr, ks * 4 + lq)];
            acc = __builtin_amdgcn_mfma_f32_16x16x32_f16(bf, tf[ks], acc, 0, 0, 0);
        }
        float4 b4 = *(const float4*)&bias2[n * 16 + (lq << 2)];
        half4 o;
        if (RES) {
            half4 hr = *(const half4*)&hres16[(size_t)min(r0 + lr, M - 1) * H + n * 16 + (lq << 2)];
            o[0] = (_Float16)(acc[0] + b4.x + (float)hr[0]);
            o[1] = (_Float16)(acc[1] + b4.y + (float)hr[1]);
            o[2] = (_Float16)(acc[2] + b4.z + (float)hr[2]);
            o[3] = (_Float16)(acc[3] + b4.w + (float)hr[3]);
        } else {
            o[0] = (_Float16)(acc[0] + b4.x);
            o[1] = (_Float16)(acc[1] + b4.y);
            o[2] = (_Float16)(acc[2] + b4.z);
            o[3] = (_Float16)(acc[3] + b4.w);
        }
        *(half4*)&Ts[off8(trow + lr, (n << 2) + lq)] = o;
    }
    __syncthreads();

    if (!FIN) {
        // coalesced hout16 write from Ts (thread -> row tid>>2, 64B) + stage B3
        if (HASX) {
            for (int i = tid; i < 2048; i += 512) {
                int row = i >> 4, g = i & 15;
                *(uint4*)&Bs[bofs(row, g)] = *(const uint4*)&B3t[i * 8];
            }
        }
        {
            int row = tid >> 2, c0 = (tid & 3) << 5;
            int grow = blockIdx.x * 128 + row;
            if (grow < M) {
                #pragma unroll
                for (int q = 0; q < 4; ++q) {
                    half8 v = ts_read(Ts, row, c0 + q * 8);
                    *(half8*)&hout16[(size_t)grow * H + c0 + q * 8] = v;
                }
            }
        }
        if (HASX) {
            half8 hf[4];
            #pragma unroll
            for (int ks = 0; ks < 4; ++ks)
                hf[ks] = ts_read(Ts, trow + lr, ks * 32 + lq * 8);
            __syncthreads();
            #pragma unroll
            for (int n = 0; n < 8; ++n) {
                f32x4 acc = {0.f, 0.f, 0.f, 0.f};
                #pragma unroll
                for (int ks = 0; ks < 4; ++ks) {
                    half8 bf = *(const half8*)&Bs[bofs(n * 16 + lr, ks * 4 + lq)];
                    acc = __builtin_amdgcn_mfma_f32_16x16x32_f16(hf[ks], bf, acc, 0, 0, 0);
                }
                #pragma unroll
                for (int j = 0; j < 4; ++j) {
                    int row = r0 + 4 * lq + j;
                    if (row < M) xout[(size_t)row * H + n * 16 + lr] = f2h(acc[j]);
                }
            }
        }
    } else {
        // ---- FIN: pass C' (SWAPPED ssp(v@B3+b3) -> Ts) then pass D (normal, u@B4+b4 -> f32) ----
        for (int i = tid; i < 2048; i += 512) {
            int row = i >> 4, g = i & 15;
            *(uint4*)&Bs[bofs(row, g)] = *(const uint4*)&B3t[i * 8];
        }
        half8 vf[4];
        #pragma unroll
        for (int ks = 0; ks < 4; ++ks)
            vf[ks] = ts_read(Ts, trow + lr, ks * 32 + lq * 8);
        __syncthreads();
        #pragma unroll
        for (int n = 0; n < 8; ++n) {
            f32x4 acc = {0.f, 0.f, 0.f, 0.f};
            #pragma unroll
            for (int ks = 0; ks < 4; ++ks) {
                half8 bf = *(const half8*)&Bs[bofs(n * 16 + lr, ks * 4 + lq)];
                acc = __builtin_amdgcn_mfma_f32_16x16x32_f16(bf, vf[ks], acc, 0, 0, 0);
            }
            float4 b4 = *(const float4*)&bias3[n * 16 + (lq << 2)];
            half4 o;
            o[0] = (_Float16)sspf(acc[0] + b4.x);
            o[1] = (_Float16)sspf(acc[1] + b4.y);
            o[2] = (_Float16)sspf(acc[2] + b4.z);
            o[3] = (_Float16)sspf(acc[3] + b4.w);
            *(half4*)&Ts[off8(trow + lr, (n << 2) + lq)] = o;
        }
        __syncthreads();
        for (int i = tid; i < 2048; i += 512) {
            int row = i >> 4, g = i & 15;
            *(uint4*)&Bs[bofs(row, g)] = *(const uint4*)&B4t[i * 8];
        }
        half8 uf[4];
        #pragma unroll
        for (int ks = 0; ks < 4; ++ks)
            uf[ks] = ts_read(Ts, trow + lr, ks * 32 + lq * 8);
        __syncthreads();
        #pragma unroll
        for (int n = 0; n < 8; ++n) {
            f32x4 acc = {0.f, 0.f, 0.f, 0.f};
            #pragma unroll
            for (int ks = 0; ks < 4; ++ks) {
                half8 bf = *(const half8*)&Bs[bofs(n * 16 + lr, ks * 4 + lq)];
                acc = __builtin_amdgcn_mfma_f32_16x16x32_f16(uf[ks], bf, acc, 0, 0, 0);
            }
            float b = bias4[n * 16 + lr];
            #pragma unroll
            for (int j = 0; j < 4; ++j) {
                int row = r0 + 4 * lq + j;
                if (row < M) houtf[(size_t)row * H + n * 16 + lr] = acc[j] + b;
            }
        }
    }
}

// ---------------- edge aggregation: degree-sorted + dispatch-interleaved ----------------

__global__ __launch_bounds__(256) void edge_agg(const int* __restrict__ deg,
                                                const int* __restrict__ order,
                                                const unsigned* __restrict__ meta,
                                                const unsigned short* __restrict__ x,
                                                const unsigned short* __restrict__ wt,
                                                unsigned short* __restrict__ agg) {
    int wv = threadIdx.x >> 6, ln = threadIdx.x & 63;
    int a = ln >> 4, fl = ln & 15;
    int gw = (blockIdx.x << 2) + wv;               // 12500 waves (NA=50000, 4 atoms/wave)
    int chunk = (gw % 250) * 50 + (gw / 250);      // bijective interleave over 12500 chunks
    int pos = (chunk << 2) + a;
    int i = order[pos];
    int n8 = (min(deg[i], PAD) + 7) & ~7;
    const unsigned* mrow = meta + (size_t)i * PAD;
    int f8 = fl << 3;
    float acc[8] = {};
    for (int p = 0; p < n8; p += 8) {
        unsigned mm[8];
        #pragma unroll
        for (int j = 0; j < 8; ++j) mm[j] = mrow[p + j];
        uint4 xv[8], wv8[8];
        #pragma unroll
        for (int j = 0; j < 8; ++j) {
            unsigned s = mm[j] & 0xFFFFu, idx = mm[j] >> 16;
            xv[j]  = *(const uint4*)(x  + ((size_t)s   << 7) + f8);
            wv8[j] = *(const uint4*)(wt + ((size_t)idx << 7) + f8);
        }
        #pragma unroll
        for (int j = 0; j < 8; ++j) {
            acc[0] += hlo(xv[j].x) * hlo(wv8[j].x);
            acc[1] += hhi(xv[j].x) * hhi(wv8[j].x);
            acc[2] += hlo(xv[j].y) * hlo(wv8[j].y);
            acc[3] += hhi(xv[j].y) * hhi(wv8[j].y);
            acc[4] += hlo(xv[j].z) * hlo(wv8[j].z);
            acc[5] += hhi(xv[j].z) * hhi(wv8[j].z);
            acc[6] += hlo(xv[j].w) * hlo(wv8[j].w);
            acc[7] += hhi(xv[j].w) * hhi(wv8[j].w);
        }
    }
    uint4 ov;
    ov.x = (unsigned)f2h(acc[0]) | ((unsigned)f2h(acc[1]) << 16);
    ov.y = (unsigned)f2h(acc[2]) | ((unsigned)f2h(acc[3]) << 16);
    ov.z = (unsigned)f2h(acc[4]) | ((unsigned)f2h(acc[5]) << 16);
    ov.w = (unsigned)f2h(acc[6]) | ((unsigned)f2h(acc[7]) << 16);
    *(uint4*)&agg[((size_t)i << 7) + f8] = ov;
}

// ---------------- readout ----------------

__global__ void mol_bounds(const int* __restrict__ a2c, const int* __restrict__ c2m,
                           int* __restrict__ ms, int* __restrict__ me) {
    int i = blockIdx.x * 256 + threadIdx.x;
    if (i >= NA) return;
    int m = c2m[a2c[i]];
    int mp = (i == 0) ? -1 : c2m[a2c[i - 1]];
    if (m != mp) ms[m] = i;
    int mn = (i == NA - 1) ? -1 : c2m[a2c[i + 1]];
    if (m != mn) me[m] = i + 1;
}

__global__ __launch_bounds__(512) void mol_sum(const int* __restrict__ ms, const int* __restrict__ me,
                                               const float* __restrict__ h2buf, float* __restrict__ mol) {
    __shared__ float red[4][128];
    int m = blockIdx.x;
    int f = threadIdx.x & 127, q = threadIdx.x >> 7;
    float acc = 0.f;
    int e0 = ms[m], e1 = me[m];
    for (int i = e0 + q; i < e1; i += 4) acc += h2buf[((size_t)i << 7) + f];
    red[q][f] = acc;
    __syncthreads();
    if (q == 0) mol[(m << 7) + f] = red[0][f] + red[1][f] + red[2][f] + red[3][f];
}

__global__ void final_mlp(const float* __restrict__ mol, const float* __restrict__ h1w,
                          const float* __restrict__ h1b, const float* __restrict__ h2w,
                          const float* __restrict__ h2b, float* __restrict__ out) {
    int m = blockIdx.x;
    int j = threadIdx.x;
    float acc = h1b[j];
    for (int k = 0; k < H; ++k) acc += mol[(m << 7) + k] * h1w[k * 64 + j];
    float hv = sspf(acc) * h2w[j];
    #pragma unroll
    for (int off = 32; off > 0; off >>= 1) hv += __shfl_down(hv, off);
    if (j == 0) out[m] = hv + h2b[0];
}

} // namespace

extern "C" void kernel_launch(void* const* d_in, const int* in_sizes, int n_in,
                              void* d_out, int out_size, void* d_ws, size_t ws_size,
                              hipStream_t stream) {
    const int*   z    = (const int*)d_in[0];
    const float* pos  = (const float*)d_in[1];
    const int*   ei   = (const int*)d_in[2];
    const int*   a2c  = (const int*)d_in[3];
    const int*   c2m  = (const int*)d_in[4];
    const float* emb  = (const float*)d_in[5];
    const float* iw1  = (const float*)d_in[6];
    const float* ib1  = (const float*)d_in[7];
    const float* iw2  = (const float*)d_in[8];
    const float* ib2  = (const float*)d_in[9];
    const float* il1  = (const float*)d_in[10];
    const float* il2w = (const float*)d_in[11];
    const float* il2b = (const float*)d_in[12];
    const float* ilw  = (const float*)d_in[13];
    const float* ilb  = (const float*)d_in[14];
    const float* l1w  = (const float*)d_in[15];
    const float* l1b  = (const float*)d_in[16];
    const float* l2w  = (const float*)d_in[17];
    const float* l2b  = (const float*)d_in[18];
    const float* h1w  = (const float*)d_in[19];
    const float* h1b  = (const float*)d_in[20];
    const float* h2w  = (const float*)d_in[21];
    const float* h2b  = (const float*)d_in[22];
    float* out = (float*)d_out;
    (void)in_sizes; (void)n_in; (void)out_size; (void)ws_size;

    char* base = (char*)d_ws;
    size_t off = 0;
    auto carve = [&](size_t bytes) -> char* {
        char* p = base + off;
        off += (bytes + 255) & ~(size_t)255;
        return p;
    };
    unsigned short* hb    = (unsigned short*)carve((size_t)NA * H * 2);
    unsigned short* xb    = (unsigned short*)carve((size_t)NA * H * 2);
    float*          agg   = (float*)carve((size_t)NA * H * 4);   // f16 during loop, f32 at end
    unsigned short* wtab  = (unsigned short*)carve((size_t)L * TSTR * 2);
    unsigned*       meta  = (unsigned*)carve(((size_t)NA * PAD + 16) * 4);
    int*            counts= (int*)carve((size_t)NA * 4);
    int*            order = (int*)carve((size_t)NA * 4);
    int*            part  = (int*)carve((size_t)SB * (PAD + 1) * 4);
    int*            ms    = (int*)carve((size_t)NM * 4);
    int*            me    = (int*)carve((size_t)NM * 4);
    float*          mol   = (float*)carve((size_t)NM * H * 4);
    unsigned short* il1t  = (unsigned short*)carve((size_t)L * H * H * 2);
    unsigned short* il2wt = (unsigned short*)carve((size_t)L * H * H * 2);
    unsigned short* ilwt  = (unsigned short*)carve((size_t)L * H * H * 2);
    unsigned short* iw2t  = (unsigned short*)carve((size_t)L * H * H * 2);
    unsigned short* l1wt  = (unsigned short*)carve((size_t)H * H * 2);
    unsigned short* l2wt  = (unsigned short*)carve((size_t)H * H * 2);
    unsigned short* iw1t  = (unsigned short*)carve((size_t)L * H * 64 * 2);
    unsigned short* aggh  = (unsigned short*)agg;

    hipMemsetAsync(counts, 0, (size_t)NA * 4, stream);
    hipMemsetAsync(meta, 0, ((size_t)NA * PAD + 16) * 4, stream);  // pad slots = (s=0, row 0 = zero)
    edge_build<<<NE / 256, 256, 0, stream>>>(pos, ei, counts, meta);
    sort_hist<<<SB, 256, 0, stream>>>(counts, part);
    sort_scan<<<1, 128, 0, stream>>>(part);
    sort_scatter<<<SB, 256, 0, stream>>>(counts, part, order);

    prep_weights<<<dim3(64, 32), 256, 0, stream>>>(il1, il2w, ilw, iw2, l1w, l2w, iw1,
                                                   il1t, il2wt, ilwt, iw2t, l1wt, l2wt, iw1t);
    table_gemm<<<dim3(TBL / 64, L), 256, 0, stream>>>(iw1t, ib1, iw2t, ib2, wtab);

    const int NG  = (NA + 63) / 64;    // 782  (gemm_hx, 64 rows/block)
    const int NGn = (NA + 127) / 128;  // 391  (node_fused, 128 rows/block)
    gemm_hx<<<NG, 256, 0, stream>>>(z, emb, il1t, hb, xb, NA);
    for (int k = 0; k < L; ++k) {
        edge_agg<<<NA / 16, 256, 0, stream>>>(counts, order, meta, xb,
                                              wtab + (size_t)k * TSTR, aggh);
        if (k < L - 1) {
            node_fused<1, 1, 0><<<NGn, 512, 0, stream>>>(aggh,
                il2b + (size_t)k * H, il2wt + (size_t)k * H * H,
                hb, hb, nullptr, ilb + (size_t)k * H, ilwt + (size_t)k * H * H,
                il1t + (size_t)(k + 1) * H * H, nullptr, nullptr, nullptr, xb, NA);
        } else {
            // last layer fused with final ssp(h@l1w+l1b)@l2w+l2b -> agg (f32)
            node_fused<1, 0, 1><<<NGn, 512, 0, stream>>>(aggh,
                il2b + (size_t)k * H, il2wt + (size_t)k * H * H,
                hb, nullptr, agg, ilb + (size_t)k * H, ilwt + (size_t)k * H * H,
                l1wt, l1b, l2wt, l2b, nullptr, NA);
        }
    }

    hipMemsetAsync(ms, 0, (size_t)NM * 4, stream);
    hipMemsetAsync(me, 0, (size_t)NM * 4, stream);
    mol_bounds<<<(NA + 255) / 256, 256, 0, stream>>>(a2c, c2m, ms, me);
    mol_sum<<<NM, 512, 0, stream>>>(ms, me, agg, mol);
    final_mlp<<<NM, 64, 0, stream>>>(mol, h1w, h1b, h2w, h2b, out);
}